// Round 10
// baseline (2466.477 us; speedup 1.0000x reference)
//
#include <hip/hip_runtime.h>

#define NEG_INF (-3.402823466e+38f)  // -FLT_MAX

// ============== DIAG A: sequential coalesced read, 6 passes (~6.29 GB) ======
__global__ __launch_bounds__(256) void diag_seq(const float4* __restrict__ x4,
                                                int n4, float* __restrict__ ws) {
    const int stride = gridDim.x * 256;
    float acc = 0.f;
#pragma unroll 1
    for (int pass = 0; pass < 6; ++pass) {
#pragma unroll 1
        for (int i = blockIdx.x * 256 + threadIdx.x; i < n4; i += stride) {
            float4 a = x4[i];
            acc += a.x + a.y + a.z + a.w;
        }
    }
    if (acc == 12345.6789f) ws[threadIdx.x] = acc;  // un-DCE-able, never fires
}

// ============== DIAG B: R8's exact access pattern, 6 passes (~6.29 GB) ======
// quad-split: 4 lanes/row, wave instr touches 16 rows x 64 B.
__global__ __launch_bounds__(512) void diag_pat(const float4* __restrict__ x4,
                                                float* __restrict__ ws) {
    const int t = threadIdx.x;
    const int wv = t >> 6;
    const int l = t & 63;
    const int q = l & 3;
    const long long row = (long long)blockIdx.x * 128 + wv * 16 + (l >> 2);
    const float4* __restrict__ pr = x4 + row * 250;
    float acc = 0.f;
#pragma unroll 1
    for (int pass = 0; pass < 6; ++pass) {
#pragma unroll 1
        for (int s = 0; s < 63; ++s) {
            int off = 4 * s + q;
            off = off < 249 ? off : 249;   // same clamp as R8's prefetch
            float4 a = pr[off];
            acc += a.x + a.y + a.z + a.w;
        }
    }
    if (acc == 12345.6789f) ws[t] = acc;
}

// ===================== REAL KERNEL: R8 (best known, 202.2 us), unchanged ====
template <int CTRL>
__device__ __forceinline__ float qperm(float v) {
    return __int_as_float(__builtin_amdgcn_update_dpp(
        __float_as_int(v), __float_as_int(v), CTRL, 0xF, 0xF, false));
}

__device__ __forceinline__ void insert12(float L[12], const float v) {
    const float p0 = L[0], p1 = L[1], p2 = L[2], p3 = L[3], p4 = L[4],
                p5 = L[5], p6 = L[6], p7 = L[7], p8 = L[8], p9 = L[9],
                p10 = L[10];
    L[0] = fmaxf(p0, v);
    L[1] = __builtin_amdgcn_fmed3f(v, p0, p1);
    L[2] = __builtin_amdgcn_fmed3f(v, p1, p2);
    L[3] = __builtin_amdgcn_fmed3f(v, p2, p3);
    L[4] = __builtin_amdgcn_fmed3f(v, p3, p4);
    L[5] = __builtin_amdgcn_fmed3f(v, p4, p5);
    L[6] = __builtin_amdgcn_fmed3f(v, p5, p6);
    L[7] = __builtin_amdgcn_fmed3f(v, p6, p7);
    L[8] = __builtin_amdgcn_fmed3f(v, p7, p8);
    L[9] = __builtin_amdgcn_fmed3f(v, p8, p9);
    L[10] = __builtin_amdgcn_fmed3f(v, p9, p10);
    L[11] = __builtin_amdgcn_fmed3f(v, p10, L[11]);
}

template <int MODE>
__device__ __forceinline__ void chunk(const float4 a, const int q,
                                      float& cy, float& cz, float& cw,
                                      float L[12]) {
    const float dy = qperm<0x90>(a.y);
    const float dz = qperm<0x90>(a.z);
    const float dw = qperm<0x90>(a.w);
    const bool q0 = (q == 0);
    const float p1 = q0 ? cw : dw;
    const float p2 = q0 ? cz : dz;
    const float p3 = q0 ? cy : dy;
    float w0 = a.x + p1 + p2 + p3;
    float w1 = w0 + a.y - p3;
    float w2 = w1 + a.z - p2;
    float w3 = w2 + a.w - p1;
    if (MODE == 0) {
        w0 = q0 ? NEG_INF : w0;
        w1 = q0 ? NEG_INF : w1;
        w2 = q0 ? NEG_INF : w2;
    }
    if (MODE == 2) {
        const bool inv = (q >= 2);
        w0 = inv ? NEG_INF : w0;
        w1 = inv ? NEG_INF : w1;
        w2 = inv ? NEG_INF : w2;
        w3 = inv ? NEG_INF : w3;
    }
    cy = qperm<0xFF>(a.y);
    cz = qperm<0xFF>(a.z);
    cw = qperm<0xFF>(a.w);
    insert12(L, w0);
    insert12(L, w1);
    insert12(L, w2);
    insert12(L, w3);
}

__global__ __launch_bounds__(512) void ssrp_quad_kernel(const float* __restrict__ x,
                                                        float* __restrict__ out) {
    __shared__ float wsum[8];
    const int t = threadIdx.x;
    const int wv = t >> 6;
    const int l = t & 63;
    const int q = l & 3;

    const long long row = (long long)blockIdx.x * 128 + wv * 16 + (l >> 2);
    const float4* __restrict__ pr = (const float4*)x + row * 250;

    float L[12];
#pragma unroll
    for (int j = 0; j < 12; ++j) L[j] = NEG_INF;
    float cy = 0.f, cz = 0.f, cw = 0.f;

    float4 a = pr[q];
    float4 b = pr[4 + q];
    {
        float4 nb = pr[8 + q];
        chunk<0>(a, q, cy, cz, cw, L);
        a = b; b = nb;
    }
#pragma unroll 2
    for (int s = 1; s <= 60; ++s) {
        int off = (s + 2) * 4 + q;
        off = off < 249 ? off : 249;
        float4 nb = pr[off];
        chunk<1>(a, q, cy, cz, cw, L);
        a = b; b = nb;
    }
    chunk<1>(a, q, cy, cz, cw, L);
    chunk<2>(b, q, cy, cz, cw, L);

    float s12 = 0.f;
#pragma unroll
    for (int rd = 0; rd < 12; ++rd) {
        const float h = L[0];
        float g = fmaxf(h, qperm<0xB1>(h));
        g = fmaxf(g, qperm<0x4E>(g));
        s12 += g;
        const unsigned long long ball = __ballot(h == g);
        const unsigned qm = (unsigned)(ball >> (l & ~3)) & 0xFu;
        const bool pop = (q == (int)__builtin_ctz(qm));
#pragma unroll
        for (int i = 0; i < 11; ++i) L[i] = pop ? L[i + 1] : L[i];
        L[11] = pop ? NEG_INF : L[11];
    }

    float contrib = (q == 0) ? s12 : 0.f;
    contrib += __shfl_xor(contrib, 4, 64);
    contrib += __shfl_xor(contrib, 8, 64);
    contrib += __shfl_xor(contrib, 16, 64);
    contrib += __shfl_xor(contrib, 32, 64);
    if (l == 0) wsum[wv] = contrib;
    __syncthreads();

    if (t == 0) {
        float s = 0.f;
#pragma unroll
        for (int i = 0; i < 8; ++i) s += wsum[i];
        out[blockIdx.x] = s * (1.0f / 6144.0f);
    }
}

extern "C" void kernel_launch(void* const* d_in, const int* in_sizes, int n_in,
                              void* d_out, int out_size, void* d_ws, size_t ws_size,
                              hipStream_t stream) {
    const float* x = (const float*)d_in[0];
    float* out = (float*)d_out;
    float* ws = (float*)d_ws;
    const long long total = (long long)in_sizes[0];  // 16*128*128*1000
    const int n4 = (int)(total / 4);                 // 65,536,000 float4s
    const int rows = (int)(total / 1000);            // 262144
    const int blocks = rows / 128;                   // 2048 == out_size

    // real kernel first (cold caches, production-like)
    hipLaunchKernelGGL(ssrp_quad_kernel, dim3(blocks), dim3(512), 0, stream, x, out);

    // diagnostics (each ~6.29 GB of reads; sized to crack the top-5)
    hipLaunchKernelGGL(diag_seq, dim3(2048), dim3(256), 0, stream,
                       (const float4*)x, n4, ws);
    hipLaunchKernelGGL(diag_pat, dim3(2048), dim3(512), 0, stream,
                       (const float4*)x, ws);
}

// Round 11
// 201.850 us; speedup vs baseline: 12.2194x; 12.2194x over previous
//
#include <hip/hip_runtime.h>

#define NEG_INF (-3.402823466e+38f)  // -FLT_MAX

// quad_perm DPP (VALU pipe). CTRL = quad_perm selector byte.
// 0x90 = [0,0,1,2]: lane q gets lane q-1 (q>=1); 0xFF = bcast lane 3
// 0xB1 = [1,0,3,2]: xor1 swap; 0x4E = [2,3,0,1]: xor2 swap
template <int CTRL>
__device__ __forceinline__ float qperm(float v) {
    return __int_as_float(__builtin_amdgcn_update_dpp(
        __float_as_int(v), __float_as_int(v), CTRL, 0xF, 0xF, false));
}

// Insert v into sorted-descending top-12 L. new L[j] = med3(v, L[j-1], L[j])
// (valid because L[j-1] >= L[j]); one VALU op per level, dependency depth 1.
__device__ __forceinline__ void insert12(float L[12], const float v) {
    const float p0 = L[0], p1 = L[1], p2 = L[2], p3 = L[3], p4 = L[4],
                p5 = L[5], p6 = L[6], p7 = L[7], p8 = L[8], p9 = L[9],
                p10 = L[10];
    L[0] = fmaxf(p0, v);
    L[1] = __builtin_amdgcn_fmed3f(v, p0, p1);
    L[2] = __builtin_amdgcn_fmed3f(v, p1, p2);
    L[3] = __builtin_amdgcn_fmed3f(v, p2, p3);
    L[4] = __builtin_amdgcn_fmed3f(v, p3, p4);
    L[5] = __builtin_amdgcn_fmed3f(v, p4, p5);
    L[6] = __builtin_amdgcn_fmed3f(v, p5, p6);
    L[7] = __builtin_amdgcn_fmed3f(v, p6, p7);
    L[8] = __builtin_amdgcn_fmed3f(v, p7, p8);
    L[9] = __builtin_amdgcn_fmed3f(v, p8, p9);
    L[10] = __builtin_amdgcn_fmed3f(v, p9, p10);
    L[11] = __builtin_amdgcn_fmed3f(v, p10, L[11]);
}

// One chunk: lane holds float4 a = its 4 consecutive elements of its row.
// prev-3 from lane q-1 via quad_perm (q>=1) or inter-chunk carry (q==0).
// MODE: 0 = first chunk (mask e<3), 1 = mid, 2 = tail (lanes q>=2 invalid).
template <int MODE>
__device__ __forceinline__ void chunk(const float4 a, const int q,
                                      float& cy, float& cz, float& cw,
                                      float L[12]) {
    const float dy = qperm<0x90>(a.y);
    const float dz = qperm<0x90>(a.z);
    const float dw = qperm<0x90>(a.w);
    const bool q0 = (q == 0);
    const float p1 = q0 ? cw : dw;  // element e-1
    const float p2 = q0 ? cz : dz;  // element e-2
    const float p3 = q0 ? cy : dy;  // element e-3
    float w0 = a.x + p1 + p2 + p3;
    float w1 = w0 + a.y - p3;
    float w2 = w1 + a.z - p2;
    float w3 = w2 + a.w - p1;
    if (MODE == 0) {  // windows ending at e=0,1,2 don't exist (lane q==0 only)
        w0 = q0 ? NEG_INF : w0;
        w1 = q0 ? NEG_INF : w1;
        w2 = q0 ? NEG_INF : w2;
    }
    if (MODE == 2) {  // tail: elements 1000..1007 invalid (lanes q>=2)
        const bool inv = (q >= 2);
        w0 = inv ? NEG_INF : w0;
        w1 = inv ? NEG_INF : w1;
        w2 = inv ? NEG_INF : w2;
        w3 = inv ? NEG_INF : w3;
    }
    // carry for next chunk's q==0 lane: this chunk's lane-3 y,z,w
    cy = qperm<0xFF>(a.y);
    cz = qperm<0xFF>(a.z);
    cw = qperm<0xFF>(a.w);
    insert12(L, w0);
    insert12(L, w1);
    insert12(L, w2);
    insert12(L, w3);
}

// 4 lanes/row, 16 rows/wave, 8 waves/block -> 128 rows = 1 output element.
// Wave load instr touches 16 cache lines (coalesced-grade); no DS ops in the
// hot loop (all cross-lane via DPP); selection = med3 sorted-insert per lane
// + 12-round quad max-extraction merge. Measured 202.2 us = 5.18 TB/s, ~97%
// of this access-pattern family's measured ceiling (diag R10).
__global__ __launch_bounds__(512) void ssrp_quad_kernel(const float* __restrict__ x,
                                                        float* __restrict__ out) {
    __shared__ float wsum[8];
    const int t = threadIdx.x;
    const int wv = t >> 6;
    const int l = t & 63;
    const int q = l & 3;

    const long long row = (long long)blockIdx.x * 128 + wv * 16 + (l >> 2);
    const float4* __restrict__ pr = (const float4*)x + row * 250;

    float L[12];
#pragma unroll
    for (int j = 0; j < 12; ++j) L[j] = NEG_INF;
    float cy = 0.f, cz = 0.f, cw = 0.f;

    // chunk s covers elements 16s..16s+15; lane's float4 col = 4s+q (<=249)
    float4 a = pr[q];        // chunk 0
    float4 b = pr[4 + q];    // chunk 1
    {
        float4 nb = pr[8 + q];               // chunk 2
        chunk<0>(a, q, cy, cz, cw, L);
        a = b; b = nb;
    }
#pragma unroll 2
    for (int s = 1; s <= 60; ++s) {
        int off = (s + 2) * 4 + q;           // chunk s+2; max 251 at s=60
        off = off < 249 ? off : 249;         // clamp tail lanes (masked later)
        float4 nb = pr[off];
        chunk<1>(a, q, cy, cz, cw, L);       // process chunk s
        a = b; b = nb;
    }
    chunk<1>(a, q, cy, cz, cw, L);           // chunk 61 (all valid)
    chunk<2>(b, q, cy, cz, cw, L);           // chunk 62 (tail: e 992..999)

    // ---- merge the 4 sorted per-lane lists: 12-round quad max-extraction
    float s12 = 0.f;
#pragma unroll
    for (int rd = 0; rd < 12; ++rd) {
        const float h = L[0];
        float g = fmaxf(h, qperm<0xB1>(h));
        g = fmaxf(g, qperm<0x4E>(g));        // quad max, same in all 4 lanes
        s12 += g;
        const unsigned long long ball = __ballot(h == g);
        const unsigned qm = (unsigned)(ball >> (l & ~3)) & 0xFu;
        const bool pop = (q == (int)__builtin_ctz(qm));  // unique winner
#pragma unroll
        for (int i = 0; i < 11; ++i) L[i] = pop ? L[i + 1] : L[i];
        L[11] = pop ? NEG_INF : L[11];
    }

    // s12 identical across the 4 lanes of a quad; q==0 reps, wave-sum
    float contrib = (q == 0) ? s12 : 0.f;
    contrib += __shfl_xor(contrib, 4, 64);
    contrib += __shfl_xor(contrib, 8, 64);
    contrib += __shfl_xor(contrib, 16, 64);
    contrib += __shfl_xor(contrib, 32, 64);
    if (l == 0) wsum[wv] = contrib;
    __syncthreads();

    if (t == 0) {
        float s = 0.f;
#pragma unroll
        for (int i = 0; i < 8; ++i) s += wsum[i];
        out[blockIdx.x] = s * (1.0f / 6144.0f);  // / (W=4 * K=12 * F=128)
    }
}

extern "C" void kernel_launch(void* const* d_in, const int* in_sizes, int n_in,
                              void* d_out, int out_size, void* d_ws, size_t ws_size,
                              hipStream_t stream) {
    const float* x = (const float*)d_in[0];
    float* out = (float*)d_out;
    const long long total = (long long)in_sizes[0];  // 16*128*128*1000
    const int rows = (int)(total / 1000);            // 262144
    const int blocks = rows / 128;                   // 2048 == out_size
    hipLaunchKernelGGL(ssrp_quad_kernel, dim3(blocks), dim3(512), 0, stream, x, out);
}